// Round 9
// baseline (162.239 us; speedup 1.0000x reference)
//
#include <hip/hip_runtime.h>
#include <stdint.h>

// ===========================================================================
// AnchorDataGenerator (Faster R-CNN anchor target layer), MI355X / gfx950
// Round 12 = R11 (98.8us, passed) + three critical-path cuts:
//   1) candidate counters/lists fanned out 32-way (R4 lesson re-applied:
//      ~250 same-address RMWs on OFF_CNT* was ~7us of serial chain)
//   2) candidates-first emit: push cands -> vmcnt(0) -> barrier D -> bulk
//      label/wts stores AFTER (fixup overlaps bulk emit; disjoint writers)
//   3) NBIN 2048->512: global hist atomics ~400K -> ~245K (fixup O(C^2)
//      still trivial at C~1000; per-group list cap 128, overflow P~1e-40
//      since mantissas are PRF-uniform by construction)
// Kept verbatim: analytic gmax, IoU/labels/adj, tree arrival barriers,
// fanned CFLAG spin, memset+worker 2-dispatch structure, agent-scope
// relaxed atomics only, vmcnt(0) before every arrival RMW.
// ===========================================================================

#define NUM_A 9
#define HW 65536
#define N_ANCH 589824
#define NG 64
#define CAPK 128u
#define NBIN 512
#define BIN_SHIFT 14
#define CLIST_CAP 128u
#define NGRP 32
#define GATHER_CAP 2048u

#define LAB_BG 0u
#define LAB_FG 1u
#define LAB_IGN 2u

#define NBLK 576

// workspace layout (u32 units)
#define OFF_HF    0                      // 512 fg hist
#define OFF_HB    NBIN                   // 512 bg hist
#define OFF_ROOTB (2*NBIN)               // 1024
#define OFF_ROOTD (2*NBIN + 1)           // 1025
#define OFF_SEL   1032                   // ..1039 {bin,below,need,K} x2
#define OFF_SUBB  1040                   // 32 x stride16
#define OFF_SUBD  (OFF_SUBB + 32*16)     // 1552
#define OFF_CFLG  (OFF_SUBD + 32*16)     // 2064
#define OFF_CCNTF (OFF_CFLG + 32*16)     // 2576: 32 x stride16
#define OFF_CCNTB (OFF_CCNTF + 32*16)    // 3088
#define CTRL_WORDS (OFF_CCNTB + 32*16)   // 3600 words = 14.4 KB memset
#define OFF_CANDF CTRL_WORDS             // 3600 (byte 14400, 8B aligned)
#define OFF_CANDB (OFF_CANDF + 2*NGRP*CLIST_CAP) // 11792; end 19984 (~80KB)

#define MAGIC_C 0x5CA1AB1Eu

__constant__ float BA[NUM_A][4] = {
  { -84.f,  -40.f,  99.f,  55.f}, {-176.f,  -88.f, 191.f, 103.f},
  {-360.f, -184.f, 375.f, 199.f}, { -56.f,  -56.f,  71.f,  71.f},
  {-120.f, -120.f, 135.f, 135.f}, {-248.f, -248.f, 263.f, 263.f},
  { -36.f,  -80.f,  51.f,  95.f}, { -80.f, -168.f,  95.f, 183.f},
  {-168.f, -344.f, 183.f, 359.f}};

__host__ __device__ static inline void tf2x32(uint32_t k0, uint32_t k1,
                                              uint32_t x0, uint32_t x1,
                                              uint32_t* o0, uint32_t* o1) {
  const uint32_t ks2 = k0 ^ k1 ^ 0x1BD11BDAu;
#define TF_R(r) { x0 += x1; x1 = (x1 << (r)) | (x1 >> (32 - (r))); x1 ^= x0; }
  x0 += k0; x1 += k1;
  TF_R(13) TF_R(15) TF_R(26) TF_R(6)
  x0 += k1;  x1 += ks2 + 1u;
  TF_R(17) TF_R(29) TF_R(16) TF_R(24)
  x0 += ks2; x1 += k0 + 2u;
  TF_R(13) TF_R(15) TF_R(26) TF_R(6)
  x0 += k0;  x1 += k1 + 3u;
  TF_R(17) TF_R(29) TF_R(16) TF_R(24)
  x0 += k1;  x1 += ks2 + 4u;
  TF_R(13) TF_R(15) TF_R(26) TF_R(6)
  x0 += ks2; x1 += k0 + 5u;
#undef TF_R
  *o0 = x0; *o1 = x1;
}

__device__ static inline uint32_t mant_of(uint32_t k0, uint32_t k1, uint32_t n) {
  uint32_t o0, o1;
  tf2x32(k0, k1, 0u, n, &o0, &o1);
  return (o0 ^ o1) >> 9;
}

// Max of fl(iw) over valid integer shifts [lo,hi] for one axis (concave,
// unimodal; max at clamped floor/ceil of continuous argmax endpoints).
__device__ static inline float axis_best(float blo, float bhi, float glo,
                                         float ghi, int lo, int hi) {
  #pragma clang fp contract(off)
  float t1 = (ghi - bhi) * 0.0625f;
  float t2 = (glo - blo) * 0.0625f;
  float tmin = fminf(t1, t2), tmax = fmaxf(t1, t2);
  int c1 = (int)floorf(tmin), c2 = (int)ceilf(tmax);
  int cand0 = lo, cand1 = hi;
  int cand2 = min(max(c1,     lo), hi);
  int cand3 = min(max(c1 + 1, lo), hi);
  int cand4 = min(max(c2 - 1, lo), hi);
  int cand5 = min(max(c2,     lo), hi);
  float best = -3.0e38f;
  int cands[6] = {cand0, cand1, cand2, cand3, cand4, cand5};
  #pragma unroll
  for (int i = 0; i < 6; i++) {
    float s = (float)(cands[i] << 4);
    float v = fminf(bhi + s, ghi) - fmaxf(blo + s, glo) + 1.0f;
    best = fmaxf(best, v);
  }
  return best;
}

#define AG_LOAD(p)      __hip_atomic_load((p), __ATOMIC_RELAXED, __HIP_MEMORY_SCOPE_AGENT)
#define AG_STORE(p, v)  __hip_atomic_store((p), (v), __ATOMIC_RELAXED, __HIP_MEMORY_SCOPE_AGENT)

__global__ __launch_bounds__(256) void k_one(const float* __restrict__ gt,
                                             const int* __restrict__ imw_p,
                                             const int* __restrict__ imh_p,
                                             float* __restrict__ out_lab,
                                             float* __restrict__ out_adj,
                                             float* __restrict__ out_wts,
                                             uint32_t* __restrict__ ws,
                                             uint32_t kf0, uint32_t kf1,
                                             uint32_t kb0, uint32_t kb1) {
  #pragma clang fp contract(off)
  __shared__ uint64_t scB[GATHER_CAP];       // 16 KB; hist view + fixup view
  uint32_t* sh = (uint32_t*)scB;             // [0..1023] = fg/bg LDS hist
  __shared__ float sg0[NG], sg1[NG], sg2[NG], sg3[NG], sga[NG], sgm[NG];
  __shared__ uint32_t sgmU[NG];
  __shared__ unsigned long long sMask[4];
  __shared__ int sAnyZero, sLastB, sLastD;
  __shared__ uint32_t sSel[8];
  int tid = threadIdx.x;
  int b = blockIdx.x;
  int a = b >> 6, hb = (b & 63) << 2;        // anchor type, rows hb..hb+3

  ((uint4*)sh)[tid] = make_uint4(0, 0, 0, 0);  // zero 1024-word LDS hist
  if (tid == 0) sAnyZero = 0;
  if (tid < NG) {
    const float4 g4 = ((const float4*)gt)[tid];
    sg0[tid] = g4.x; sg1[tid] = g4.y; sg2[tid] = g4.z; sg3[tid] = g4.w;
    float gw = g4.z - g4.x + 1.0f, gh = g4.w - g4.y + 1.0f;
    sga[tid] = (gw > 0.0f && gh > 0.0f) ? gw * gh : 0.0f;
    sgmU[tid] = 0u;
  }
  __syncthreads();   // S1

  // ---- local analytic gmax (LDS atomicMax on float bits; IoU >= 0) ----
  {
    int imwi = imw_p[0], imhi = imh_p[0];
    for (int p = tid; p < NG * NUM_A; p += 256) {
      int g = p / NUM_A, q = p - g * NUM_A;
      float b0 = BA[q][0], b1 = BA[q][1], b2 = BA[q][2], b3 = BA[q][3];
      int ib0 = (int)b0, ib1 = (int)b1, ib2 = (int)b2, ib3 = (int)b3;
      int wlo = max(0, (-ib0 + 15) >> 4);
      int whi = min(255, (imwi - ib2 - 1) >> 4);
      int hlo = max(0, (-ib1 + 15) >> 4);
      int hhi = min(255, (imhi - ib3 - 1) >> 4);
      if (wlo > whi || hlo > hhi) continue;
      float iwb = axis_best(b0, b2, sg0[g], sg2[g], wlo, whi);
      float ihb = axis_best(b1, b3, sg1[g], sg3[g], hlo, hhi);
      float aw = b2 - b0 + 1.0f, ah = b3 - b1 + 1.0f;
      float aarea = aw * ah;
      float inter = (iwb > 0.0f && ihb > 0.0f) ? iwb * ihb : 0.0f;
      float den = aarea + sga[g] - inter;
      float o = inter / den;
      atomicMax(&sgmU[g], __float_as_uint(o));
    }
  }

  // per-wave y-mask
  {
    int wv = tid >> 6, g = tid & 63;
    float sy = (float)((hb + wv) << 4);
    float ihp = fminf(BA[a][3] + sy, sg3[g]) - fmaxf(BA[a][1] + sy, sg1[g]) + 1.0f;
    unsigned long long mk = __ballot(ihp > 0.0f);
    if (g == 0) sMask[wv] = mk;
  }
  __syncthreads();   // S2
  if (tid < NG) {
    uint32_t mm = sgmU[tid];
    sgm[tid] = __uint_as_float(mm);
    if (mm == 0u) atomicOr(&sAnyZero, 1);
  }
  __syncthreads();   // S3

  float BA0 = BA[a][0], BA1 = BA[a][1], BA2 = BA[a][2], BA3 = BA[a][3];
  float imw = (float)imw_p[0], imh = (float)imh_p[0];
  int w = tid;
  float sx = (float)(w << 4);
  float A0 = BA0 + sx, A2 = BA2 + sx;
  float aw = A2 - A0 + 1.0f;
  float A1v[4], A3v[4];
  #pragma unroll
  for (int r = 0; r < 4; r++) {
    float sy = (float)((hb + r) << 4);
    A1v[r] = BA1 + sy; A3v[r] = BA3 + sy;
  }
  float ah = A3v[0] - A1v[0] + 1.0f;
  float aarea = aw * ah;
  bool xv = (A0 >= 0.0f) && (A2 < imw);

  unsigned long long mk0 = sMask[0], mk1 = sMask[1],
                     mk2 = sMask[2], mk3 = sMask[3];
  unsigned long long uni = mk0 | mk1 | mk2 | mk3;
  float amaxv[4] = {0.f, 0.f, 0.f, 0.f};
  int bgv[4] = {0, 0, 0, 0};
  uint32_t afv = 0u;
  while (uni) {
    int g = __ffsll(uni) - 1;
    uni &= uni - 1;
    float iw = fminf(A2, sg2[g]) - fmaxf(A0, sg0[g]) + 1.0f;
    if (!__any(iw > 0.0f)) continue;
    if (iw > 0.0f) {
      float base = aarea + sga[g];
      float gy1 = sg1[g], gy2 = sg3[g], gm = sgm[g];
#define DO_ROW(r, mk)                                                     \
      if ((mk >> g) & 1ull) {                                             \
        float ih = fminf(A3v[r], gy2) - fmaxf(A1v[r], gy1) + 1.0f;        \
        float inter = iw * ih;                                            \
        float o = inter / (base - inter);                                 \
        if (o > amaxv[r]) { amaxv[r] = o; bgv[r] = g; }                   \
        if (o == gm) afv |= (1u << r);                                    \
      }
      DO_ROW(0, mk0) DO_ROW(1, mk1) DO_ROW(2, mk2) DO_ROW(3, mk3)
#undef DO_ROW
    }
  }

  bool anyZ = (sAnyZero != 0);
  uint32_t lm[4];
  #pragma unroll
  for (int r = 0; r < 4; r++) {
    int hw = (hb + r) * 256 + w;
    bool valid = xv && (A1v[r] >= 0.0f) && (A3v[r] < imh);
    float amax = amaxv[r];
    bool anyfg = (((afv >> r) & 1u) || anyZ) && valid;
    uint32_t lab;
    if (!valid)                       lab = LAB_IGN;
    else if (anyfg || amax >= 0.7f)   lab = LAB_FG;
    else if (amax < 0.3f)             lab = LAB_BG;
    else                              lab = LAB_IGN;

    float adj0 = 0.f, adj1 = 0.f, adj2 = 0.f, adj3 = 0.f;
    if (valid) {
      int bg = bgv[r];
      float G0 = sg0[bg], G1 = sg1[bg], G2 = sg2[bg], G3 = sg3[bg];
      float ax = (A2 + A0) * 0.5f, ay = (A3v[r] + A1v[r]) * 0.5f;
      float gwm = G2 - G0 + 1.0f, ghm = G3 - G1 + 1.0f;
      float gx = (G2 + G0) * 0.5f, gy = (G3 + G1) * 0.5f;
      adj0 = (gx - ax) / aw;
      adj1 = (gy - ay) / ah;
      adj2 = logf(gwm / aw);
      adj3 = logf(ghm / ah);
    }
    int c4 = a * 4;
    out_adj[(c4 + 0) * HW + hw] = adj0;
    out_adj[(c4 + 1) * HW + hw] = adj1;
    out_adj[(c4 + 2) * HW + hw] = adj2;
    out_adj[(c4 + 3) * HW + hw] = adj3;

    uint32_t m = 0u;
    uint32_t n = (uint32_t)(hw * 9 + a);
    if (lab != LAB_IGN) {
      uint32_t kk0 = (lab == LAB_FG) ? kf0 : kb0;
      uint32_t kk1 = (lab == LAB_FG) ? kf1 : kb1;
      m = mant_of(kk0, kk1, n);
      atomicAdd(&sh[((lab == LAB_FG) ? 0 : NBIN) + (m >> BIN_SHIFT)], 1u);
    }
    lm[r] = (lab << 24) | m;                 // stays in registers
  }
  __syncthreads();

  // ---- global hist add (ctrl region pre-zeroed by stream-ordered memset) --
  for (int i = tid; i < 2 * NBIN; i += 256) {
    uint32_t v = sh[i];
    if (v) atomicAdd(&ws[OFF_HF + i], v);
  }
  asm volatile("s_waitcnt vmcnt(0)" ::: "memory");
  __syncthreads();

  // ---- barrier B: tree arrival; completer runs select ----
  if (tid == 0) {
    int last = 0;
    uint32_t v = atomicAdd(&ws[OFF_SUBB + (b & 31) * 16], 1u);
    if (v == 17u) {
      uint32_t r = atomicAdd(&ws[OFF_ROOTB], 1u);
      if (r == 31u) last = 1;
    }
    sLastB = last;
  }
  __syncthreads();
  if (sLastB) {
    for (int cls = 0; cls < 2; cls++) {
      uint32_t* hist = ws + (cls ? OFF_HB : OFF_HF);
      uint32_t* sel = ws + OFF_SEL + cls * 4;
      uint32_t loc[2], s = 0;
      #pragma unroll
      for (int j = 0; j < 2; j++) {
        loc[j] = AG_LOAD(&hist[tid * 2 + j]);
        s += loc[j];
      }
      sh[tid] = s; __syncthreads();
      for (int off = 1; off < 256; off <<= 1) {
        uint32_t v = (tid >= off) ? sh[tid - off] : 0u;
        __syncthreads();
        sh[tid] += v;
        __syncthreads();
      }
      uint32_t total = sh[255];
      uint32_t K = total < CAPK ? total : CAPK;
      if (tid == 0) {
        AG_STORE(&sel[3], K);
        if (K == 0u) {
          AG_STORE(&sel[0], 0xFFFFFFFFu); AG_STORE(&sel[1], 0u);
          AG_STORE(&sel[2], 0u);
        }
      }
      if (K > 0u) {
        uint32_t myC = sh[tid], pvC = (tid == 0) ? 0u : sh[tid - 1];
        if (myC >= K && pvC < K) {
          uint32_t cum = pvC; int bb = tid * 2;
          #pragma unroll
          for (int j = 0; j < 2; j++) {
            if (cum + loc[j] >= K) { bb = tid * 2 + j; break; }
            cum += loc[j];
          }
          AG_STORE(&sel[0], (uint32_t)bb); AG_STORE(&sel[1], cum);
          AG_STORE(&sel[2], K - cum);
        }
      }
      __syncthreads();
    }
    asm volatile("s_waitcnt vmcnt(0)" ::: "memory");
    __syncthreads();                         // all SEL stores at IF
    if (tid < 32) AG_STORE(&ws[OFF_CFLG + tid * 16], MAGIC_C);
  }

  // ---- fanned-out wake: poll OWN sub-flag (<=18 pollers/address) ----
  if (tid == 0) {
    while (AG_LOAD(&ws[OFF_CFLG + (b & 31) * 16]) != MAGIC_C)
      __builtin_amdgcn_s_sleep(2);
  }
  __syncthreads();
  if (tid < 8) sSel[tid] = AG_LOAD(&ws[OFF_SEL + tid]);
  __syncthreads();
  uint32_t bf = sSel[0], Kf = sSel[3], bbn = sSel[4], Kb = sSel[7];
  float inv = 1.0f / (float)(Kf + Kb);       // 1/num_ni

  // ---- pass 1: candidate pushes ONLY (fanned 32-way lists) ----
  uint32_t pushedMask = 0u;
  #pragma unroll
  for (int r = 0; r < 4; r++) {
    uint32_t lab = lm[r] >> 24;
    if (lab == LAB_IGN) continue;
    uint32_t m = lm[r] & 0x7FFFFFu;
    uint32_t bn = m >> BIN_SHIFT;
    uint32_t bnd = (lab == LAB_FG) ? bf : bbn;
    if (bn == bnd) {
      int hw = (hb + r) * 256 + w;
      uint32_t n = (uint32_t)(hw * 9 + a);
      uint32_t grp = (uint32_t)(b & 31);
      uint32_t cbase = (lab == LAB_FG) ? OFF_CCNTF : OFF_CCNTB;
      uint32_t idx = atomicAdd(&ws[cbase + grp * 16], 1u);
      if (idx < CLIST_CAP) {
        uint64_t* lst = (uint64_t*)(ws + ((lab == LAB_FG) ? OFF_CANDF
                                                          : OFF_CANDB)) +
                        grp * CLIST_CAP;
        AG_STORE(&lst[idx], ((uint64_t)m << 20) | (uint64_t)n);
        pushedMask |= (1u << r);
      }
    }
  }
  asm volatile("s_waitcnt vmcnt(0)" ::: "memory");
  __syncthreads();

  // ---- barrier D: tree arrival; completer runs fixup (overlaps others'
  // bulk emit below — writer sets are disjoint) ----
  if (tid == 0) {
    int last = 0;
    uint32_t v = atomicAdd(&ws[OFF_SUBD + (b & 31) * 16], 1u);
    if (v == 17u) {
      uint32_t r = atomicAdd(&ws[OFF_ROOTD], 1u);
      if (r == 31u) last = 1;
    }
    sLastD = last;
  }
  __syncthreads();
  if (sLastD) {
    uint64_t* sc = scB;
    for (int cls = 0; cls < 2; cls++) {
      // gather 32 per-group lists into contiguous LDS
      uint32_t total = 0;
      for (int g2 = 0; g2 < NGRP; g2++) {
        uint32_t cg = AG_LOAD(&ws[(cls ? OFF_CCNTB : OFF_CCNTF) + g2 * 16]);
        cg = cg < CLIST_CAP ? cg : CLIST_CAP;
        if (total + cg > GATHER_CAP) cg = GATHER_CAP - total;
        const uint64_t* lst =
            (const uint64_t*)(ws + (cls ? OFF_CANDB : OFF_CANDF)) +
            g2 * CLIST_CAP;
        for (uint32_t i = tid; i < cg; i += 256)
          sc[total + i] = AG_LOAD(&lst[i]);
        total += cg;
      }
      __syncthreads();
      uint32_t C = total;
      uint32_t need = AG_LOAD(&ws[OFF_SEL + cls * 4 + 2]);
      for (uint32_t i = tid; i < C; i += 256) {
        uint64_t k = sc[i];
        uint32_t rr = 0;
        for (uint32_t j = 0; j < C; j++) rr += (sc[j] < k) ? 1u : 0u;
        bool kept = (rr < need);             // keys unique -> exactly need
        uint32_t nn = (uint32_t)(k & 0xFFFFFu);
        uint32_t aa = nn % 9u, hww = nn / 9u;
        uint32_t tt = aa * HW + hww;
        float lv = kept ? (cls == 0 ? 1.0f : 0.0f) : 2.0f;
        float wvv = (kept && cls == 0) ? inv : 0.0f;
        AG_STORE(&out_lab[tt], lv);
        #pragma unroll
        for (int j2 = 0; j2 < 4; j2++)
          AG_STORE(&out_wts[(aa * 4 + j2) * HW + hww], wvv);
      }
      __syncthreads();
    }
  }

  // ---- pass 2: bulk emit for non-candidate anchors (no barrier needed;
  // disjoint from fixup's writes) ----
  #pragma unroll
  for (int r = 0; r < 4; r++) {
    if ((pushedMask >> r) & 1u) continue;
    int hw = (hb + r) * 256 + w;
    uint32_t lab = lm[r] >> 24;
    uint32_t m = lm[r] & 0x7FFFFFu;
    float outv = 2.0f, wv = 0.0f;
    if (lab == LAB_FG) {
      uint32_t bn = m >> BIN_SHIFT;
      if (bn < bf) { outv = 1.0f; wv = inv; }
    } else if (lab == LAB_BG) {
      uint32_t bn = m >> BIN_SHIFT;
      if (bn < bbn) outv = 0.0f;
    }
    out_lab[a * HW + hw] = outv;
    int c4 = a * 4;
    out_wts[(c4 + 0) * HW + hw] = wv;
    out_wts[(c4 + 1) * HW + hw] = wv;
    out_wts[(c4 + 2) * HW + hw] = wv;
    out_wts[(c4 + 3) * HW + hw] = wv;
  }
}

extern "C" void kernel_launch(void* const* d_in, const int* in_sizes, int n_in,
                              void* d_out, int out_size, void* d_ws,
                              size_t ws_size, hipStream_t stream) {
  const float* gt  = (const float*)d_in[1];
  const int*   imw = (const int*)d_in[2];
  const int*   imh = (const int*)d_in[3];
  float* out      = (float*)d_out;
  float* out_lab  = out;                   // 589824
  float* out_adj  = out + N_ANCH;          // 4*589824
  float* out_wts  = out + 5 * N_ANCH;      // 4*589824
  uint32_t* ws = (uint32_t*)d_ws;          // ~80 KB used

  uint32_t kf0, kf1, kb0, kb1;
  tf2x32(0u, 42u, 0u, 0u, &kf0, &kf1);
  tf2x32(0u, 42u, 0u, 1u, &kb0, &kb1);

  // Stream-ordered zero of ctrl region (hists, roots, SEL, sub-counters,
  // CFLAG, candidate counters): every run starts clean.
  hipMemsetAsync(ws, 0, CTRL_WORDS * sizeof(uint32_t), stream);
  // Residency by capacity: 576 blocks, ~18KB LDS -> 8 blocks/CU (2048
  // slots) >> 576, low VGPR; sole kernel on the stream -> all co-resident.
  hipLaunchKernelGGL(k_one, dim3(NBLK), dim3(256), 0, stream, gt, imw, imh,
                     out_lab, out_adj, out_wts, ws, kf0, kf1, kb0, kb1);
}

// Round 10
// 103.949 us; speedup vs baseline: 1.5608x; 1.5608x over previous
//
#include <hip/hip_runtime.h>
#include <stdint.h>

// ===========================================================================
// AnchorDataGenerator (Faster R-CNN anchor target layer), MI355X / gfx950
// Round 13 = R12 structure with the two R12 regressions reverted/fixed:
//   - NBIN back to 2048 (R12's 512 made boundary-bin C ~780 -> O(C^2) x16,
//     and DEEPENED per-address hist chains ~280x28ns; chain depth, not
//     total count, is the cost variable)
//   - fixup gather PARALLELIZED (R12's serial per-group AG_LOAD loop was
//     64 dependent ~900-cycle IF round-trips = the 100us single-block tail
//     seen as OccupancyPercent 7.2%). New rule: agent-scope loads bypass
//     caches; issue them in parallel, never serially dependent.
// Kept: 32-way fanned candidate lists, candidates-first emit (barrier D
// before bulk stores; fixup overlaps bulk emit, writer sets disjoint),
// tree arrival barriers, fanned CFLAG wake, memset+worker 2-dispatch,
// agent-scope relaxed atomics only, vmcnt(0) before every arrival RMW.
// ===========================================================================

#define NUM_A 9
#define HW 65536
#define N_ANCH 589824
#define NG 64
#define CAPK 128u
#define NBIN 2048
#define BIN_SHIFT 12
#define CLIST_CAP 128u
#define NGRP 32
#define GATHER_CAP 2048u

#define LAB_BG 0u
#define LAB_FG 1u
#define LAB_IGN 2u

#define NBLK 576

// workspace layout (u32 units)
#define OFF_HF    0                      // 2048 fg hist
#define OFF_HB    NBIN                   // 2048 bg hist
#define OFF_ROOTB (2*NBIN)               // 4096
#define OFF_ROOTD (2*NBIN + 1)           // 4097
#define OFF_SEL   4104                   // ..4111 {bin,below,need,K} x2
#define OFF_SUBB  4112                   // 32 x stride16
#define OFF_SUBD  (OFF_SUBB + 32*16)     // 4624
#define OFF_CFLG  (OFF_SUBD + 32*16)     // 5136
#define OFF_CCNTF (OFF_CFLG + 32*16)     // 5648: 32 x stride16
#define OFF_CCNTB (OFF_CCNTF + 32*16)    // 6160
#define CTRL_WORDS (OFF_CCNTB + 32*16)   // 6672 words = 26.7 KB memset
#define OFF_CANDF CTRL_WORDS             // 6672 (byte 26688, 8B aligned)
#define OFF_CANDB (OFF_CANDF + 2*NGRP*CLIST_CAP) // 14864; end 23056 (~92KB)

#define MAGIC_C 0x5CA1AB1Eu

__constant__ float BA[NUM_A][4] = {
  { -84.f,  -40.f,  99.f,  55.f}, {-176.f,  -88.f, 191.f, 103.f},
  {-360.f, -184.f, 375.f, 199.f}, { -56.f,  -56.f,  71.f,  71.f},
  {-120.f, -120.f, 135.f, 135.f}, {-248.f, -248.f, 263.f, 263.f},
  { -36.f,  -80.f,  51.f,  95.f}, { -80.f, -168.f,  95.f, 183.f},
  {-168.f, -344.f, 183.f, 359.f}};

__host__ __device__ static inline void tf2x32(uint32_t k0, uint32_t k1,
                                              uint32_t x0, uint32_t x1,
                                              uint32_t* o0, uint32_t* o1) {
  const uint32_t ks2 = k0 ^ k1 ^ 0x1BD11BDAu;
#define TF_R(r) { x0 += x1; x1 = (x1 << (r)) | (x1 >> (32 - (r))); x1 ^= x0; }
  x0 += k0; x1 += k1;
  TF_R(13) TF_R(15) TF_R(26) TF_R(6)
  x0 += k1;  x1 += ks2 + 1u;
  TF_R(17) TF_R(29) TF_R(16) TF_R(24)
  x0 += ks2; x1 += k0 + 2u;
  TF_R(13) TF_R(15) TF_R(26) TF_R(6)
  x0 += k0;  x1 += k1 + 3u;
  TF_R(17) TF_R(29) TF_R(16) TF_R(24)
  x0 += k1;  x1 += ks2 + 4u;
  TF_R(13) TF_R(15) TF_R(26) TF_R(6)
  x0 += ks2; x1 += k0 + 5u;
#undef TF_R
  *o0 = x0; *o1 = x1;
}

__device__ static inline uint32_t mant_of(uint32_t k0, uint32_t k1, uint32_t n) {
  uint32_t o0, o1;
  tf2x32(k0, k1, 0u, n, &o0, &o1);
  return (o0 ^ o1) >> 9;
}

// Max of fl(iw) over valid integer shifts [lo,hi] for one axis (concave,
// unimodal; max at clamped floor/ceil of continuous argmax endpoints).
__device__ static inline float axis_best(float blo, float bhi, float glo,
                                         float ghi, int lo, int hi) {
  #pragma clang fp contract(off)
  float t1 = (ghi - bhi) * 0.0625f;
  float t2 = (glo - blo) * 0.0625f;
  float tmin = fminf(t1, t2), tmax = fmaxf(t1, t2);
  int c1 = (int)floorf(tmin), c2 = (int)ceilf(tmax);
  int cand0 = lo, cand1 = hi;
  int cand2 = min(max(c1,     lo), hi);
  int cand3 = min(max(c1 + 1, lo), hi);
  int cand4 = min(max(c2 - 1, lo), hi);
  int cand5 = min(max(c2,     lo), hi);
  float best = -3.0e38f;
  int cands[6] = {cand0, cand1, cand2, cand3, cand4, cand5};
  #pragma unroll
  for (int i = 0; i < 6; i++) {
    float s = (float)(cands[i] << 4);
    float v = fminf(bhi + s, ghi) - fmaxf(blo + s, glo) + 1.0f;
    best = fmaxf(best, v);
  }
  return best;
}

#define AG_LOAD(p)      __hip_atomic_load((p), __ATOMIC_RELAXED, __HIP_MEMORY_SCOPE_AGENT)
#define AG_STORE(p, v)  __hip_atomic_store((p), (v), __ATOMIC_RELAXED, __HIP_MEMORY_SCOPE_AGENT)

__global__ __launch_bounds__(256) void k_one(const float* __restrict__ gt,
                                             const int* __restrict__ imw_p,
                                             const int* __restrict__ imh_p,
                                             float* __restrict__ out_lab,
                                             float* __restrict__ out_adj,
                                             float* __restrict__ out_wts,
                                             uint32_t* __restrict__ ws,
                                             uint32_t kf0, uint32_t kf1,
                                             uint32_t kb0, uint32_t kb1) {
  #pragma clang fp contract(off)
  __shared__ uint64_t scB[GATHER_CAP];       // 16 KB; hist view + fixup view
  uint32_t* sh = (uint32_t*)scB;             // [0..4095] = fg/bg LDS hist
  __shared__ float sg0[NG], sg1[NG], sg2[NG], sg3[NG], sga[NG], sgm[NG];
  __shared__ uint32_t sgmU[NG];
  __shared__ unsigned long long sMask[4];
  __shared__ int sAnyZero, sLastB, sLastD;
  __shared__ uint32_t sSel[8];
  __shared__ uint32_t sCnt[NGRP], sBase[NGRP], sTot;
  int tid = threadIdx.x;
  int b = blockIdx.x;
  int a = b >> 6, hb = (b & 63) << 2;        // anchor type, rows hb..hb+3

  {
    uint4* sh4 = (uint4*)sh;
    #pragma unroll
    for (int k = 0; k < 4; k++) sh4[tid + k * 256] = make_uint4(0, 0, 0, 0);
  }
  if (tid == 0) sAnyZero = 0;
  if (tid < NG) {
    const float4 g4 = ((const float4*)gt)[tid];
    sg0[tid] = g4.x; sg1[tid] = g4.y; sg2[tid] = g4.z; sg3[tid] = g4.w;
    float gw = g4.z - g4.x + 1.0f, gh = g4.w - g4.y + 1.0f;
    sga[tid] = (gw > 0.0f && gh > 0.0f) ? gw * gh : 0.0f;
    sgmU[tid] = 0u;
  }
  __syncthreads();   // S1

  // ---- local analytic gmax (LDS atomicMax on float bits; IoU >= 0) ----
  {
    int imwi = imw_p[0], imhi = imh_p[0];
    for (int p = tid; p < NG * NUM_A; p += 256) {
      int g = p / NUM_A, q = p - g * NUM_A;
      float b0 = BA[q][0], b1 = BA[q][1], b2 = BA[q][2], b3 = BA[q][3];
      int ib0 = (int)b0, ib1 = (int)b1, ib2 = (int)b2, ib3 = (int)b3;
      int wlo = max(0, (-ib0 + 15) >> 4);
      int whi = min(255, (imwi - ib2 - 1) >> 4);
      int hlo = max(0, (-ib1 + 15) >> 4);
      int hhi = min(255, (imhi - ib3 - 1) >> 4);
      if (wlo > whi || hlo > hhi) continue;
      float iwb = axis_best(b0, b2, sg0[g], sg2[g], wlo, whi);
      float ihb = axis_best(b1, b3, sg1[g], sg3[g], hlo, hhi);
      float aw = b2 - b0 + 1.0f, ah = b3 - b1 + 1.0f;
      float aarea = aw * ah;
      float inter = (iwb > 0.0f && ihb > 0.0f) ? iwb * ihb : 0.0f;
      float den = aarea + sga[g] - inter;
      float o = inter / den;
      atomicMax(&sgmU[g], __float_as_uint(o));
    }
  }

  // per-wave y-mask
  {
    int wv = tid >> 6, g = tid & 63;
    float sy = (float)((hb + wv) << 4);
    float ihp = fminf(BA[a][3] + sy, sg3[g]) - fmaxf(BA[a][1] + sy, sg1[g]) + 1.0f;
    unsigned long long mk = __ballot(ihp > 0.0f);
    if (g == 0) sMask[wv] = mk;
  }
  __syncthreads();   // S2
  if (tid < NG) {
    uint32_t mm = sgmU[tid];
    sgm[tid] = __uint_as_float(mm);
    if (mm == 0u) atomicOr(&sAnyZero, 1);
  }
  __syncthreads();   // S3

  float BA0 = BA[a][0], BA1 = BA[a][1], BA2 = BA[a][2], BA3 = BA[a][3];
  float imw = (float)imw_p[0], imh = (float)imh_p[0];
  int w = tid;
  float sx = (float)(w << 4);
  float A0 = BA0 + sx, A2 = BA2 + sx;
  float aw = A2 - A0 + 1.0f;
  float A1v[4], A3v[4];
  #pragma unroll
  for (int r = 0; r < 4; r++) {
    float sy = (float)((hb + r) << 4);
    A1v[r] = BA1 + sy; A3v[r] = BA3 + sy;
  }
  float ah = A3v[0] - A1v[0] + 1.0f;
  float aarea = aw * ah;
  bool xv = (A0 >= 0.0f) && (A2 < imw);

  unsigned long long mk0 = sMask[0], mk1 = sMask[1],
                     mk2 = sMask[2], mk3 = sMask[3];
  unsigned long long uni = mk0 | mk1 | mk2 | mk3;
  float amaxv[4] = {0.f, 0.f, 0.f, 0.f};
  int bgv[4] = {0, 0, 0, 0};
  uint32_t afv = 0u;
  while (uni) {
    int g = __ffsll(uni) - 1;
    uni &= uni - 1;
    float iw = fminf(A2, sg2[g]) - fmaxf(A0, sg0[g]) + 1.0f;
    if (!__any(iw > 0.0f)) continue;
    if (iw > 0.0f) {
      float base = aarea + sga[g];
      float gy1 = sg1[g], gy2 = sg3[g], gm = sgm[g];
#define DO_ROW(r, mk)                                                     \
      if ((mk >> g) & 1ull) {                                             \
        float ih = fminf(A3v[r], gy2) - fmaxf(A1v[r], gy1) + 1.0f;        \
        float inter = iw * ih;                                            \
        float o = inter / (base - inter);                                 \
        if (o > amaxv[r]) { amaxv[r] = o; bgv[r] = g; }                   \
        if (o == gm) afv |= (1u << r);                                    \
      }
      DO_ROW(0, mk0) DO_ROW(1, mk1) DO_ROW(2, mk2) DO_ROW(3, mk3)
#undef DO_ROW
    }
  }

  bool anyZ = (sAnyZero != 0);
  uint32_t lm[4];
  #pragma unroll
  for (int r = 0; r < 4; r++) {
    int hw = (hb + r) * 256 + w;
    bool valid = xv && (A1v[r] >= 0.0f) && (A3v[r] < imh);
    float amax = amaxv[r];
    bool anyfg = (((afv >> r) & 1u) || anyZ) && valid;
    uint32_t lab;
    if (!valid)                       lab = LAB_IGN;
    else if (anyfg || amax >= 0.7f)   lab = LAB_FG;
    else if (amax < 0.3f)             lab = LAB_BG;
    else                              lab = LAB_IGN;

    float adj0 = 0.f, adj1 = 0.f, adj2 = 0.f, adj3 = 0.f;
    if (valid) {
      int bg = bgv[r];
      float G0 = sg0[bg], G1 = sg1[bg], G2 = sg2[bg], G3 = sg3[bg];
      float ax = (A2 + A0) * 0.5f, ay = (A3v[r] + A1v[r]) * 0.5f;
      float gwm = G2 - G0 + 1.0f, ghm = G3 - G1 + 1.0f;
      float gx = (G2 + G0) * 0.5f, gy = (G3 + G1) * 0.5f;
      adj0 = (gx - ax) / aw;
      adj1 = (gy - ay) / ah;
      adj2 = logf(gwm / aw);
      adj3 = logf(ghm / ah);
    }
    int c4 = a * 4;
    out_adj[(c4 + 0) * HW + hw] = adj0;
    out_adj[(c4 + 1) * HW + hw] = adj1;
    out_adj[(c4 + 2) * HW + hw] = adj2;
    out_adj[(c4 + 3) * HW + hw] = adj3;

    uint32_t m = 0u;
    uint32_t n = (uint32_t)(hw * 9 + a);
    if (lab != LAB_IGN) {
      uint32_t kk0 = (lab == LAB_FG) ? kf0 : kb0;
      uint32_t kk1 = (lab == LAB_FG) ? kf1 : kb1;
      m = mant_of(kk0, kk1, n);
      atomicAdd(&sh[((lab == LAB_FG) ? 0 : NBIN) + (m >> BIN_SHIFT)], 1u);
    }
    lm[r] = (lab << 24) | m;                 // stays in registers
  }
  __syncthreads();

  // ---- global hist add (ctrl region pre-zeroed by stream-ordered memset) --
  for (int i = tid; i < 2 * NBIN; i += 256) {
    uint32_t v = sh[i];
    if (v) atomicAdd(&ws[OFF_HF + i], v);
  }
  asm volatile("s_waitcnt vmcnt(0)" ::: "memory");
  __syncthreads();

  // ---- barrier B: tree arrival; completer runs select ----
  if (tid == 0) {
    int last = 0;
    uint32_t v = atomicAdd(&ws[OFF_SUBB + (b & 31) * 16], 1u);
    if (v == 17u) {
      uint32_t r = atomicAdd(&ws[OFF_ROOTB], 1u);
      if (r == 31u) last = 1;
    }
    sLastB = last;
  }
  __syncthreads();
  if (sLastB) {
    for (int cls = 0; cls < 2; cls++) {
      uint32_t* hist = ws + (cls ? OFF_HB : OFF_HF);
      uint32_t* sel = ws + OFF_SEL + cls * 4;
      uint32_t loc[8], s = 0;
      #pragma unroll
      for (int j = 0; j < 8; j++) {
        loc[j] = AG_LOAD(&hist[tid * 8 + j]);
        s += loc[j];
      }
      sh[tid] = s; __syncthreads();
      for (int off = 1; off < 256; off <<= 1) {
        uint32_t v = (tid >= off) ? sh[tid - off] : 0u;
        __syncthreads();
        sh[tid] += v;
        __syncthreads();
      }
      uint32_t total = sh[255];
      uint32_t K = total < CAPK ? total : CAPK;
      if (tid == 0) {
        AG_STORE(&sel[3], K);
        if (K == 0u) {
          AG_STORE(&sel[0], 0xFFFFFFFFu); AG_STORE(&sel[1], 0u);
          AG_STORE(&sel[2], 0u);
        }
      }
      if (K > 0u) {
        uint32_t myC = sh[tid], pvC = (tid == 0) ? 0u : sh[tid - 1];
        if (myC >= K && pvC < K) {
          uint32_t cum = pvC; int bb = tid * 8;
          #pragma unroll
          for (int j = 0; j < 8; j++) {
            if (cum + loc[j] >= K) { bb = tid * 8 + j; break; }
            cum += loc[j];
          }
          AG_STORE(&sel[0], (uint32_t)bb); AG_STORE(&sel[1], cum);
          AG_STORE(&sel[2], K - cum);
        }
      }
      __syncthreads();
    }
    asm volatile("s_waitcnt vmcnt(0)" ::: "memory");
    __syncthreads();                         // all SEL stores at IF
    if (tid < 32) AG_STORE(&ws[OFF_CFLG + tid * 16], MAGIC_C);
  }

  // ---- fanned-out wake: poll OWN sub-flag (<=18 pollers/address) ----
  if (tid == 0) {
    while (AG_LOAD(&ws[OFF_CFLG + (b & 31) * 16]) != MAGIC_C)
      __builtin_amdgcn_s_sleep(2);
  }
  __syncthreads();
  if (tid < 8) sSel[tid] = AG_LOAD(&ws[OFF_SEL + tid]);
  __syncthreads();
  uint32_t bf = sSel[0], Kf = sSel[3], bbn = sSel[4], Kb = sSel[7];
  float inv = 1.0f / (float)(Kf + Kb);       // 1/num_ni

  // ---- pass 1: candidate pushes ONLY (fanned 32-way lists) ----
  uint32_t pushedMask = 0u;
  #pragma unroll
  for (int r = 0; r < 4; r++) {
    uint32_t lab = lm[r] >> 24;
    if (lab == LAB_IGN) continue;
    uint32_t m = lm[r] & 0x7FFFFFu;
    uint32_t bn = m >> BIN_SHIFT;
    uint32_t bnd = (lab == LAB_FG) ? bf : bbn;
    if (bn == bnd) {
      int hw = (hb + r) * 256 + w;
      uint32_t n = (uint32_t)(hw * 9 + a);
      uint32_t grp = (uint32_t)(b & 31);
      uint32_t cbase = (lab == LAB_FG) ? OFF_CCNTF : OFF_CCNTB;
      uint32_t idx = atomicAdd(&ws[cbase + grp * 16], 1u);
      if (idx < CLIST_CAP) {
        uint64_t* lst = (uint64_t*)(ws + ((lab == LAB_FG) ? OFF_CANDF
                                                          : OFF_CANDB)) +
                        grp * CLIST_CAP;
        AG_STORE(&lst[idx], ((uint64_t)m << 20) | (uint64_t)n);
        pushedMask |= (1u << r);
      }
    }
  }
  asm volatile("s_waitcnt vmcnt(0)" ::: "memory");
  __syncthreads();

  // ---- barrier D: tree arrival; completer runs fixup (overlaps others'
  // bulk emit below — writer sets are disjoint) ----
  if (tid == 0) {
    int last = 0;
    uint32_t v = atomicAdd(&ws[OFF_SUBD + (b & 31) * 16], 1u);
    if (v == 17u) {
      uint32_t r = atomicAdd(&ws[OFF_ROOTD], 1u);
      if (r == 31u) last = 1;
    }
    sLastD = last;
  }
  __syncthreads();
  if (sLastD) {
    uint64_t* sc = scB;
    for (int cls = 0; cls < 2; cls++) {
      const uint64_t* lst0 =
          (const uint64_t*)(ws + (cls ? OFF_CANDB : OFF_CANDF));
      // 1) all 32 group counters loaded in PARALLEL (one IF round-trip)
      if (tid < NGRP) {
        uint32_t cg = AG_LOAD(&ws[(cls ? OFF_CCNTB : OFF_CCNTF) + tid * 16]);
        sCnt[tid] = cg < CLIST_CAP ? cg : CLIST_CAP;
      }
      __syncthreads();
      // 2) tiny prefix-sum (32 elems, one thread)
      if (tid == 0) {
        uint32_t acc = 0;
        for (int g2 = 0; g2 < NGRP; g2++) { sBase[g2] = acc; acc += sCnt[g2]; }
        sTot = acc < GATHER_CAP ? acc : GATHER_CAP;
      }
      __syncthreads();
      // 3) flattened PARALLEL gather (all list loads in flight at once)
      for (uint32_t idx = tid; idx < NGRP * CLIST_CAP; idx += 256) {
        uint32_t grp = idx >> 7;             // / CLIST_CAP
        uint32_t i = idx & (CLIST_CAP - 1u);
        if (i < sCnt[grp]) {
          uint32_t dst = sBase[grp] + i;
          if (dst < GATHER_CAP)
            sc[dst] = AG_LOAD(&lst0[grp * CLIST_CAP + i]);
        }
      }
      __syncthreads();
      uint32_t C = sTot;
      uint32_t need = AG_LOAD(&ws[OFF_SEL + cls * 4 + 2]);
      for (uint32_t i = tid; i < C; i += 256) {
        uint64_t k = sc[i];
        uint32_t rr = 0;
        for (uint32_t j = 0; j < C; j++) rr += (sc[j] < k) ? 1u : 0u;
        bool kept = (rr < need);             // keys unique -> exactly need
        uint32_t nn = (uint32_t)(k & 0xFFFFFu);
        uint32_t aa = nn % 9u, hww = nn / 9u;
        uint32_t tt = aa * HW + hww;
        float lv = kept ? (cls == 0 ? 1.0f : 0.0f) : 2.0f;
        float wvv = (kept && cls == 0) ? inv : 0.0f;
        AG_STORE(&out_lab[tt], lv);
        #pragma unroll
        for (int j2 = 0; j2 < 4; j2++)
          AG_STORE(&out_wts[(aa * 4 + j2) * HW + hww], wvv);
      }
      __syncthreads();
    }
  }

  // ---- pass 2: bulk emit for non-candidate anchors (no barrier needed;
  // disjoint from fixup's writes) ----
  #pragma unroll
  for (int r = 0; r < 4; r++) {
    if ((pushedMask >> r) & 1u) continue;
    int hw = (hb + r) * 256 + w;
    uint32_t lab = lm[r] >> 24;
    uint32_t m = lm[r] & 0x7FFFFFu;
    float outv = 2.0f, wv = 0.0f;
    if (lab == LAB_FG) {
      uint32_t bn = m >> BIN_SHIFT;
      if (bn < bf) { outv = 1.0f; wv = inv; }
    } else if (lab == LAB_BG) {
      uint32_t bn = m >> BIN_SHIFT;
      if (bn < bbn) outv = 0.0f;
    }
    out_lab[a * HW + hw] = outv;
    int c4 = a * 4;
    out_wts[(c4 + 0) * HW + hw] = wv;
    out_wts[(c4 + 1) * HW + hw] = wv;
    out_wts[(c4 + 2) * HW + hw] = wv;
    out_wts[(c4 + 3) * HW + hw] = wv;
  }
}

extern "C" void kernel_launch(void* const* d_in, const int* in_sizes, int n_in,
                              void* d_out, int out_size, void* d_ws,
                              size_t ws_size, hipStream_t stream) {
  const float* gt  = (const float*)d_in[1];
  const int*   imw = (const int*)d_in[2];
  const int*   imh = (const int*)d_in[3];
  float* out      = (float*)d_out;
  float* out_lab  = out;                   // 589824
  float* out_adj  = out + N_ANCH;          // 4*589824
  float* out_wts  = out + 5 * N_ANCH;      // 4*589824
  uint32_t* ws = (uint32_t*)d_ws;          // ~92 KB used

  uint32_t kf0, kf1, kb0, kb1;
  tf2x32(0u, 42u, 0u, 0u, &kf0, &kf1);
  tf2x32(0u, 42u, 0u, 1u, &kb0, &kb1);

  // Stream-ordered zero of ctrl region (hists, roots, SEL, sub-counters,
  // CFLAG, candidate counters): every run starts clean.
  hipMemsetAsync(ws, 0, CTRL_WORDS * sizeof(uint32_t), stream);
  // Residency by capacity: 576 blocks, ~18.5KB LDS -> 8 blocks/CU (2048
  // slots) >> 576, low VGPR; sole kernel on the stream -> all co-resident.
  hipLaunchKernelGGL(k_one, dim3(NBLK), dim3(256), 0, stream, gt, imw, imh,
                     out_lab, out_adj, out_wts, ws, kf0, kf1, kb0, kb1);
}